// Round 1
// baseline (310.189 us; speedup 1.0000x reference)
//
#include <hip/hip_runtime.h>

// ---------------------------------------------------------------------------
// Compile-time Cayley table for Cl(4,0), blades in short-lex order
// (sorted by grade=popcount, then bitmap). For each (i,k): exactly one output
// blade j = idx(ba ^ bb) with sign from the merge-swap parity (metric all +1).
// constexpr => fully folded after loop unrolling; signs become fneg on fma.
// ---------------------------------------------------------------------------
struct Tables {
    signed char  sgn[16][16];
    unsigned char out[16][16];
};

constexpr int pc4(int x) {
    return ((x >> 0) & 1) + ((x >> 1) & 1) + ((x >> 2) & 1) + ((x >> 3) & 1);
}

constexpr Tables make_tables() {
    Tables t{};
    int bitmaps[16] = {};
    int n = 0;
    for (int g = 0; g <= 4; ++g)
        for (int bm = 0; bm < 16; ++bm)
            if (pc4(bm) == g) bitmaps[n++] = bm;
    int inv[16] = {};
    for (int i = 0; i < 16; ++i) inv[bitmaps[i]] = i;
    for (int i = 0; i < 16; ++i) {
        for (int k = 0; k < 16; ++k) {
            const int ba = bitmaps[i];
            const int bb = bitmaps[k];
            int swaps = 0;
            for (int sh = ba >> 1; sh; sh >>= 1) swaps += pc4(sh & bb);
            t.sgn[i][k] = (swaps & 1) ? -1 : 1;   // metric = [1,1,1,1]: no extra sign
            t.out[i][k] = (unsigned char)inv[ba ^ bb];
        }
    }
    return t;
}

constexpr Tables TBL = make_tables();

// One thread = one multivector pair (16 floats a, 16 floats b -> 16 floats out).
// 4x float4 loads each (64B/thread); wave spans 4KiB contiguously => all HBM
// lines fully used. 256 signed FMAs per thread, all in registers.
__global__ __launch_bounds__(256) void clifford_gp_kernel(
        const float4* __restrict__ a4,
        const float4* __restrict__ b4,
        float4* __restrict__ o4,
        int n_mv) {
    const int m = blockIdx.x * blockDim.x + threadIdx.x;
    if (m >= n_mv) return;

    float av[16], bv[16], ov[16];

    #pragma unroll
    for (int q = 0; q < 4; ++q) {
        const float4 va = a4[m * 4 + q];
        av[q * 4 + 0] = va.x; av[q * 4 + 1] = va.y;
        av[q * 4 + 2] = va.z; av[q * 4 + 3] = va.w;
    }
    #pragma unroll
    for (int q = 0; q < 4; ++q) {
        const float4 vb = b4[m * 4 + q];
        bv[q * 4 + 0] = vb.x; bv[q * 4 + 1] = vb.y;
        bv[q * 4 + 2] = vb.z; bv[q * 4 + 3] = vb.w;
    }

    #pragma unroll
    for (int j = 0; j < 16; ++j) ov[j] = 0.0f;

    #pragma unroll
    for (int i = 0; i < 16; ++i) {
        #pragma unroll
        for (int k = 0; k < 16; ++k) {
            const int j = TBL.out[i][k];          // compile-time constant after unroll
            if (TBL.sgn[i][k] > 0) {
                ov[j] = fmaf(av[i], bv[k], ov[j]);
            } else {
                ov[j] = fmaf(-av[i], bv[k], ov[j]);
            }
        }
    }

    #pragma unroll
    for (int q = 0; q < 4; ++q) {
        o4[m * 4 + q] = make_float4(ov[q * 4 + 0], ov[q * 4 + 1],
                                    ov[q * 4 + 2], ov[q * 4 + 3]);
    }
}

extern "C" void kernel_launch(void* const* d_in, const int* in_sizes, int n_in,
                              void* d_out, int out_size, void* d_ws, size_t ws_size,
                              hipStream_t stream) {
    const float4* a4 = (const float4*)d_in[0];
    const float4* b4 = (const float4*)d_in[1];
    // d_in[2] (cayley) intentionally unused: table folded at compile time.
    float4* o4 = (float4*)d_out;

    const int n_mv = in_sizes[0] / 16;            // 2048*1024 = 2,097,152
    const int block = 256;
    const int grid = (n_mv + block - 1) / block;  // 8192 blocks

    clifford_gp_kernel<<<grid, block, 0, stream>>>(a4, b4, o4, n_mv);
}